// Round 3
// baseline (965.749 us; speedup 1.0000x reference)
//
#include <hip/hip_runtime.h>
#include <hip/hip_bf16.h>

#define NN 65536
#define NE 1048576
#define EW 3072   // persistent waves in k_edge (768 blocks x 4 waves)

typedef __attribute__((ext_vector_type(8))) short short8;
typedef __attribute__((ext_vector_type(4))) float f32x4;

__device__ __forceinline__ float bcast(float v, int l) {
    return __int_as_float(__builtin_amdgcn_readlane(__float_as_int(v), l));
}
__device__ __forceinline__ float lrelu(float x) { return x > 0.f ? x : 0.01f * x; }
__device__ __forceinline__ float frelu(float x) { return x > 0.f ? x : 0.f; }
__device__ __forceinline__ short f2bf(float f) {
    __hip_bfloat16 h = __float2bfloat16(f);
    return *reinterpret_cast<short*>(&h);
}
__device__ __forceinline__ float bf2f(short s) {
    return __uint_as_float(((unsigned)(unsigned short)s) << 16);
}

// ---- combined weights: Wda = W_dst@A1, Wsa = W_src@A1 ----
__global__ void k_prep(const float* __restrict__ Wdst, const float* __restrict__ Wsrc,
                       const float* __restrict__ A1, float* __restrict__ Wda,
                       float* __restrict__ Wsa) {
    int o = blockIdx.x * 256 + threadIdx.x;           // 0..8191
    const float* Wsel = (o < 4096) ? Wdst : Wsrc;
    float* Osel = (o < 4096) ? Wda : Wsa;
    int oo = o & 4095;
    int r = oo >> 6, c = oo & 63;
    float acc = 0.f;
#pragma unroll
    for (int k = 0; k < 64; ++k) acc += Wsel[r * 64 + k] * A1[k * 64 + c];
    Osel[oo] = acc;
}

// ---- pack into MFMA A-fragment layout: fid 0=P2 1=A1 2=A2 3=Wout(hi) 4=Wout(lo)
// A[m][k] = W[in = 32*s + 8*(l>>4) + b][out = 16*rb + (l&15)]
__global__ void k_pack(const float* __restrict__ P2, const float* __restrict__ A1,
                       const float* __restrict__ A2, const float* __restrict__ Wout,
                       short* __restrict__ Apack) {
    int idx = blockIdx.x * 256 + threadIdx.x;   // fid*512 + (rb*2+s)*64 + l
    if (idx >= 2560) return;
    int l = idx & 63, s = (idx >> 6) & 1, rb = (idx >> 7) & 3, fid = idx >> 9;
    const float* W = (fid == 0) ? P2 : (fid == 1) ? A1 : (fid == 2) ? A2 : Wout;
    bool lo = (fid == 4);
#pragma unroll
    for (int b = 0; b < 8; ++b) {
        int in = 32 * s + 8 * (l >> 4) + b;
        int out = 16 * rb + (l & 15);
        float w = W[in * 64 + out];
        short hi = f2bf(w);
        Apack[idx * 8 + b] = lo ? f2bf(w - bf2f(hi)) : hi;
    }
}

// ---- merged node kernel (persistent, fp32 exact):
// h=relu(x@Win+b) in reg; v=h@Wlin; ad1=h@Wda+a1; as1=h@Wsa; q=pos@P1
__global__ void __launch_bounds__(512) k_node(
    const float* __restrict__ x, const float* __restrict__ pos,
    const float* __restrict__ Win, const float* __restrict__ bin,
    const float* __restrict__ Wlin, const float* __restrict__ Wda,
    const float* __restrict__ Wsa, const float* __restrict__ P1,
    const float* __restrict__ a1,
    float* __restrict__ v, float* __restrict__ ad1,
    float* __restrict__ as1, float* __restrict__ q) {
    __shared__ float Wi[4096], Wl[4096], Wd[4096], Ws[4096], Pb[320];
    for (int idx = threadIdx.x; idx < 4096; idx += 512) {
        Wi[idx] = Win[idx]; Wl[idx] = Wlin[idx]; Wd[idx] = Wda[idx]; Ws[idx] = Wsa[idx];
    }
    if (threadIdx.x < 192) Pb[threadIdx.x] = P1[threadIdx.x];
    if (threadIdx.x < 64) {
        Pb[192 + threadIdx.x] = bin[threadIdx.x];
        Pb[256 + threadIdx.x] = a1[threadIdx.x];
    }
    __syncthreads();
    int l = threadIdx.x & 63;
    int wid = blockIdx.x * 8 + (threadIdx.x >> 6);      // 0..4095
    for (int n = wid; n < NN; n += 4096) {
        float xv = x[(size_t)n * 64 + l];
        float p0 = pos[n * 3 + 0], p1v = pos[n * 3 + 1], p2v = pos[n * 3 + 2];
        float hv = Pb[192 + l];
#pragma unroll
        for (int k = 0; k < 64; ++k) hv += bcast(xv, k) * Wi[k * 64 + l];
        hv = frelu(hv);
        float av = 0.f, bv = Pb[256 + l], cv = 0.f;
#pragma unroll
        for (int k = 0; k < 64; ++k) {
            float s = bcast(hv, k);
            av += s * Wl[k * 64 + l];
            bv += s * Wd[k * 64 + l];
            cv += s * Ws[k * 64 + l];
        }
        v[(size_t)n * 64 + l] = av;
        ad1[(size_t)n * 64 + l] = bv;
        as1[(size_t)n * 64 + l] = cv;
        q[(size_t)n * 64 + l] = p0 * Pb[l] + p1v * Pb[64 + l] + p2v * Pb[128 + l];
    }
}

// ---- CSR build (padded to 16-edge tiles) ----
__global__ void k_hist(const int* __restrict__ ei, int* __restrict__ deg) {
    int e = blockIdx.x * 256 + threadIdx.x;
    atomicAdd(&deg[ei[NE + e]], 1);
}

__global__ void k_scan(const int* __restrict__ deg, int* __restrict__ poff,
                       int* __restrict__ cur) {
    __shared__ int part[256];
    int t = threadIdx.x;
    int sum = 0;
    for (int r = 0; r < 256; ++r) sum += ((deg[t * 256 + r] + 15) >> 4) << 4;
    part[t] = sum;
    __syncthreads();
    if (t == 0) {
        int run = 0;
        for (int b = 0; b < 256; ++b) { int tmp = part[b]; part[b] = run; run += tmp; }
    }
    __syncthreads();
    int run = part[t];
    for (int r = 0; r < 256; ++r) {
        int n = t * 256 + r;
        poff[n] = run; cur[n] = run;
        run += ((deg[n] + 15) >> 4) << 4;
    }
    if (t == 255) poff[NN] = run;
}

__global__ void k_scatter(const int* __restrict__ ei, int* __restrict__ cur,
                          int* __restrict__ srtj) {
    int e = blockIdx.x * 256 + threadIdx.x;
    int i = ei[NE + e];
    int slot = atomicAdd(&cur[i], 1);
    srtj[slot] = ei[e];
}

// D-layout -> next-layer B-frag transpose via shuffles.
__device__ __forceinline__ short8 transfrag(const f32x4* X, int s, int g, int e) {
    short8 r;
#pragma unroll
    for (int b = 0; b < 8; ++b) {
        float lo = X[2 * s][b & 3], hi = X[2 * s + 1][b & 3];
        float val = (g & 2) ? hi : lo;
        val = __shfl(val, 16 * (2 * (g & 1) + (b >> 2)) + e);
        r[b] = f2bf(val);
    }
    return r;
}

#define MFMA(a, b, c) __builtin_amdgcn_mfma_f32_16x16x32_bf16(a, b, c, 0, 0, 0)

// ---- persistent fused edge MLP (MFMA) + register softmax; writes o[N,64] fp32 ----
__global__ void __launch_bounds__(256, 3) k_edge(
    const float* __restrict__ q, const float* __restrict__ ad1, const float* __restrict__ as1,
    const float* __restrict__ v, const int* __restrict__ poff, const int* __restrict__ deg,
    const int* __restrict__ srtj, const short* __restrict__ Apack,
    const float* __restrict__ p2b, const float* __restrict__ a2b,
    const float* __restrict__ p1b, float* __restrict__ o) {
    __shared__ short AwLds[12288];     // 3 layers x 4 rb x 2 s x 64 lanes x 8 bf16
    __shared__ float biasLds[192];     // [0]p2b [64]a2b [128]p1b
    {
        const int* gA = (const int*)Apack;
        int* sA = (int*)AwLds;
        for (int i = threadIdx.x; i < 6144; i += 256) sA[i] = gA[i];
        if (threadIdx.x < 64) {
            biasLds[threadIdx.x] = p2b[threadIdx.x];
            biasLds[64 + threadIdx.x] = a2b[threadIdx.x];
            biasLds[128 + threadIdx.x] = p1b[threadIdx.x];
        }
    }
    __syncthreads();

    int l = threadIdx.x & 63;
    int g = l >> 4, e = l & 15;
    int wid = blockIdx.x * 4 + (threadIdx.x >> 6);   // 0..EW-1

#define AW(L, rb, s) (*(const short8*)(AwLds + ((((L) * 4 + (rb)) * 2 + (s)) * 64 + l) * 8))

    // prologue: first node's CSR info + first tile indices
    int t0 = poff[wid], t1 = poff[wid + 1], dn = deg[wid];
    int j = (t0 < t1) ? srtj[t0 + e] : 0;

    for (int node = wid; node < NN; node += EW) {
        int nn = node + EW;
        int nt0 = 0, nt1 = 0, ndn = 0;
        if (nn < NN) { nt0 = poff[nn]; nt1 = poff[nn + 1]; ndn = deg[nn]; }

        const float* qi = q + (size_t)node * 64;
        f32x4 qpsA0 = *(const f32x4*)(qi + 8 * g)      + *(const f32x4*)(biasLds + 128 + 8 * g);
        f32x4 qpsA1 = *(const f32x4*)(qi + 8 * g + 4)  + *(const f32x4*)(biasLds + 132 + 8 * g);
        f32x4 qpsB0 = *(const f32x4*)(qi + 32 + 8 * g) + *(const f32x4*)(biasLds + 160 + 8 * g);
        f32x4 qpsB1 = *(const f32x4*)(qi + 36 + 8 * g) + *(const f32x4*)(biasLds + 164 + 8 * g);
        f32x4 advv[4];
        const float* ai = ad1 + (size_t)node * 64;
#pragma unroll
        for (int rb = 0; rb < 4; ++rb) advv[rb] = *(const f32x4*)(ai + 16 * rb + 4 * g);

        f32x4 num[4], den[4];
#pragma unroll
        for (int rb = 0; rb < 4; ++rb) { num[rb] = (f32x4)0.f; den[rb] = (f32x4)0.f; }

        for (int tb = t0; tb < t1; tb += 16) {
            int jn = (tb + 16 < t1) ? srtj[tb + 16 + e] : 0;   // prefetch next tile
            const float* qj = q + (size_t)j * 64;
            f32x4 xA0 = *(const f32x4*)(qj + 8 * g);
            f32x4 xA1 = *(const f32x4*)(qj + 8 * g + 4);
            f32x4 xB0 = *(const f32x4*)(qj + 32 + 8 * g);
            f32x4 xB1 = *(const f32x4*)(qj + 36 + 8 * g);
            short8 bu0, bu1;
#pragma unroll
            for (int b = 0; b < 4; ++b) {
                bu0[b]     = f2bf(lrelu(qpsA0[b] - xA0[b]));
                bu0[b + 4] = f2bf(lrelu(qpsA1[b] - xA1[b]));
                bu1[b]     = f2bf(lrelu(qpsB0[b] - xB0[b]));
                bu1[b + 4] = f2bf(lrelu(qpsB1[b] - xB1[b]));
            }

            // layer 1: d^T = P2^T u^T + p2b
            f32x4 acc[4];
#pragma unroll
            for (int rb = 0; rb < 4; ++rb)
                acc[rb] = *(const f32x4*)(biasLds + 16 * rb + 4 * g);
#pragma unroll
            for (int rb = 0; rb < 4; ++rb) {
                acc[rb] = MFMA(AW(0, rb, 0), bu0, acc[rb]);
                acc[rb] = MFMA(AW(0, rb, 1), bu1, acc[rb]);
            }
            f32x4 d4[4];
#pragma unroll
            for (int rb = 0; rb < 4; ++rb)
#pragma unroll
                for (int c = 0; c < 4; ++c) { float xx = acc[rb][c]; d4[rb][c] = xx > 0.f ? xx : 0.01f * xx; }

            // layer 2: t^T = A1^T d^T + (adv_i - as1_j)
            short8 bd0 = transfrag(d4, 0, g, e);
            short8 bd1 = transfrag(d4, 1, g, e);
            const float* ap = as1 + (size_t)j * 64;
#pragma unroll
            for (int rb = 0; rb < 4; ++rb)
                acc[rb] = advv[rb] - *(const f32x4*)(ap + 16 * rb + 4 * g);
#pragma unroll
            for (int rb = 0; rb < 4; ++rb) {
                acc[rb] = MFMA(AW(1, rb, 0), bd0, acc[rb]);
                acc[rb] = MFMA(AW(1, rb, 1), bd1, acc[rb]);
            }
            f32x4 t4[4];
#pragma unroll
            for (int rb = 0; rb < 4; ++rb)
#pragma unroll
                for (int c = 0; c < 4; ++c) t4[rb][c] = frelu(acc[rb][c]);

            // layer 3: alpha^T = A2^T t^T + a2b
            short8 bt0 = transfrag(t4, 0, g, e);
            short8 bt1 = transfrag(t4, 1, g, e);
#pragma unroll
            for (int rb = 0; rb < 4; ++rb)
                acc[rb] = *(const f32x4*)(biasLds + 64 + 16 * rb + 4 * g);
#pragma unroll
            for (int rb = 0; rb < 4; ++rb) {
                acc[rb] = MFMA(AW(2, rb, 0), bt0, acc[rb]);
                acc[rb] = MFMA(AW(2, rb, 1), bt1, acc[rb]);
            }

            // softmax accumulate (alpha >= 0 -> exp safe, no max pass)
            bool ok = (tb - t0 + e) < dn;
            const float* vp = v + (size_t)j * 64;
#pragma unroll
            for (int rb = 0; rb < 4; ++rb) {
                f32x4 vv = *(const f32x4*)(vp + 16 * rb + 4 * g);
                f32x4 ew;
#pragma unroll
                for (int c = 0; c < 4; ++c) {
                    float a = frelu(acc[rb][c]);
                    ew[c] = ok ? __expf(a) : 0.f;
                }
                den[rb] += ew;
                num[rb] += ew * (vv + d4[rb]);
            }
            j = jn;
        }

        // prefetch next node's first tile indices
        int jf = (nn < NN && nt0 < nt1) ? srtj[nt0 + e] : 0;

        // reduce over the 16 edge-lanes
#pragma unroll
        for (int m = 1; m < 16; m <<= 1) {
#pragma unroll
            for (int rb = 0; rb < 4; ++rb)
#pragma unroll
                for (int c = 0; c < 4; ++c) {
                    num[rb][c] += __shfl_xor(num[rb][c], m);
                    den[rb][c] += __shfl_xor(den[rb][c], m);
                }
        }
        if (e == 0) {
            float* op = o + (size_t)node * 64;
#pragma unroll
            for (int rb = 0; rb < 4; ++rb) {
                f32x4 ov;
#pragma unroll
                for (int c = 0; c < 4; ++c) ov[c] = num[rb][c] / (den[rb][c] + 1e-16f);
                *(f32x4*)(op + 16 * rb + 4 * g) = ov;
            }
        }
        t0 = nt0; t1 = nt1; dn = ndn; j = jf;
    }
#undef AW
}

// ---- out = relu(o @ Wout + bout), split-bf16 MFMA (hi/lo on both operands) ----
__global__ void __launch_bounds__(512) k_out(const float* __restrict__ o,
                                             const short* __restrict__ Apack,
                                             const float* __restrict__ bout,
                                             float* __restrict__ out) {
    __shared__ short Ah[4096], Al[4096];
    __shared__ float bb[64];
    {
        const int* gh = (const int*)(Apack + 3 * 4096);
        const int* gl = (const int*)(Apack + 4 * 4096);
        int* sh = (int*)Ah; int* sl = (int*)Al;
        for (int i = threadIdx.x; i < 2048; i += 512) { sh[i] = gh[i]; sl[i] = gl[i]; }
        if (threadIdx.x < 64) bb[threadIdx.x] = bout[threadIdx.x];
    }
    __syncthreads();
    int l = threadIdx.x & 63, g = l >> 4;
    int tile = blockIdx.x * 8 + (threadIdx.x >> 6);   // 0..4095
    int nbase = tile * 16;
    const float* op = o + (size_t)(nbase + (l & 15)) * 64;
    f32x4 s0a = *(const f32x4*)(op + 8 * g);
    f32x4 s0b = *(const f32x4*)(op + 8 * g + 4);
    f32x4 s1a = *(const f32x4*)(op + 32 + 8 * g);
    f32x4 s1b = *(const f32x4*)(op + 36 + 8 * g);
    short8 bh0, bl0, bh1, bl1;
#pragma unroll
    for (int b = 0; b < 4; ++b) {
        short h;
        h = f2bf(s0a[b]); bh0[b] = h;     bl0[b] = f2bf(s0a[b] - bf2f(h));
        h = f2bf(s0b[b]); bh0[b + 4] = h; bl0[b + 4] = f2bf(s0b[b] - bf2f(h));
        h = f2bf(s1a[b]); bh1[b] = h;     bl1[b] = f2bf(s1a[b] - bf2f(h));
        h = f2bf(s1b[b]); bh1[b + 4] = h; bl1[b + 4] = f2bf(s1b[b] - bf2f(h));
    }
#define AF(arr, rb, s) (*(const short8*)(arr + (((rb) * 2 + (s)) * 64 + l) * 8))
    f32x4 acc[4];
#pragma unroll
    for (int rb = 0; rb < 4; ++rb) acc[rb] = *(const f32x4*)(bb + 16 * rb + 4 * g);
#pragma unroll
    for (int rb = 0; rb < 4; ++rb) {
        acc[rb] = MFMA(AF(Ah, rb, 0), bh0, acc[rb]);
        acc[rb] = MFMA(AF(Ah, rb, 1), bh1, acc[rb]);
        acc[rb] = MFMA(AF(Ah, rb, 0), bl0, acc[rb]);
        acc[rb] = MFMA(AF(Ah, rb, 1), bl1, acc[rb]);
        acc[rb] = MFMA(AF(Al, rb, 0), bh0, acc[rb]);
        acc[rb] = MFMA(AF(Al, rb, 1), bh1, acc[rb]);
    }
#undef AF
    float* outp = out + (size_t)(nbase + (l & 15)) * 64;
#pragma unroll
    for (int rb = 0; rb < 4; ++rb) {
        f32x4 r;
#pragma unroll
        for (int c = 0; c < 4; ++c) r[c] = frelu(acc[rb][c]);
        *(f32x4*)(outp + 16 * rb + 4 * g) = r;
    }
}

extern "C" void kernel_launch(void* const* d_in, const int* in_sizes, int n_in,
                              void* d_out, int out_size, void* d_ws, size_t ws_size,
                              hipStream_t stream) {
    const float* x    = (const float*)d_in[0];
    const float* pos  = (const float*)d_in[1];
    const int*   ei   = (const int*)d_in[2];
    const float* Win  = (const float*)d_in[3];
    const float* bin  = (const float*)d_in[4];
    const float* Wout = (const float*)d_in[5];
    const float* bout = (const float*)d_in[6];
    const float* Wlin = (const float*)d_in[7];
    const float* Wsrc = (const float*)d_in[8];
    const float* Wdst = (const float*)d_in[9];
    const float* P1   = (const float*)d_in[10];
    const float* p1   = (const float*)d_in[11];
    const float* P2   = (const float*)d_in[12];
    const float* p2   = (const float*)d_in[13];
    const float* A1   = (const float*)d_in[14];
    const float* a1   = (const float*)d_in[15];
    const float* A2   = (const float*)d_in[16];
    const float* a2   = (const float*)d_in[17];
    float* out = (float*)d_out;

    char* w = (char*)d_ws;
    float* Wda  = (float*)w; w += 4096 * 4;
    float* Wsa  = (float*)w; w += 4096 * 4;
    short* Apck = (short*)w; w += 5 * 4096 * 2;
    float* v    = (float*)w; w += (size_t)NN * 64 * 4;
    float* ad1  = (float*)w; w += (size_t)NN * 64 * 4;
    float* as1  = (float*)w; w += (size_t)NN * 64 * 4;
    float* q    = (float*)w; w += (size_t)NN * 64 * 4;
    float* o    = (float*)w; w += (size_t)NN * 64 * 4;
    int* deg    = (int*)w; w += (size_t)NN * 4;
    int* poffp  = (int*)w; w += (size_t)(NN + 16) * 4;
    int* cur    = (int*)w; w += (size_t)NN * 4;
    int* srtj   = (int*)w; w += (size_t)2 * NE * 4;

    hipMemsetAsync(deg, 0, (size_t)NN * 4, stream);
    hipMemsetAsync(srtj, 0, (size_t)2 * NE * 4, stream);
    k_prep<<<32, 256, 0, stream>>>(Wdst, Wsrc, A1, Wda, Wsa);
    k_pack<<<10, 256, 0, stream>>>(P2, A1, A2, Wout, Apck);
    k_node<<<512, 512, 0, stream>>>(x, pos, Win, bin, Wlin, Wda, Wsa, P1, a1,
                                    v, ad1, as1, q);
    k_hist<<<NE / 256, 256, 0, stream>>>(ei, deg);
    k_scan<<<1, 256, 0, stream>>>(deg, poffp, cur);
    k_scatter<<<NE / 256, 256, 0, stream>>>(ei, cur, srtj);
    k_edge<<<EW / 4, 256, 0, stream>>>(q, ad1, as1, v, poffp, deg, srtj, Apck,
                                       p2, a2, p1, o);
    k_out<<<512, 512, 0, stream>>>(o, Apck, bout, out);
}

// Round 5
// 635.760 us; speedup vs baseline: 1.5190x; 1.5190x over previous
//
#include <hip/hip_runtime.h>
#include <hip/hip_bf16.h>

#define NN 65536
#define NE 1048576
#define EW 4096   // persistent waves in k_edge (1024 blocks x 4 waves)

typedef __attribute__((ext_vector_type(8))) short short8;
typedef __attribute__((ext_vector_type(8))) unsigned short bf16x8;
typedef __attribute__((ext_vector_type(4))) unsigned short bf16x4;
typedef __attribute__((ext_vector_type(4))) float f32x4;

__device__ __forceinline__ float bcast(float v, int l) {
    return __int_as_float(__builtin_amdgcn_readlane(__float_as_int(v), l));
}
__device__ __forceinline__ float lrelu(float x) { return x > 0.f ? x : 0.01f * x; }
__device__ __forceinline__ float frelu(float x) { return x > 0.f ? x : 0.f; }
__device__ __forceinline__ short f2bf(float f) {
    __hip_bfloat16 h = __float2bfloat16(f);
    return *reinterpret_cast<short*>(&h);
}
__device__ __forceinline__ float bf2f(unsigned short s) {
    return __uint_as_float(((unsigned)s) << 16);
}
__device__ __forceinline__ f32x4 b2f4(bf16x4 s) {
    f32x4 r;
#pragma unroll
    for (int i = 0; i < 4; ++i) r[i] = bf2f(s[i]);
    return r;
}

// ---- combined weights: Wda = W_dst@A1, Wsa = W_src@A1 ----
__global__ void k_prep(const float* __restrict__ Wdst, const float* __restrict__ Wsrc,
                       const float* __restrict__ A1, float* __restrict__ Wda,
                       float* __restrict__ Wsa) {
    int o = blockIdx.x * 256 + threadIdx.x;           // 0..8191
    const float* Wsel = (o < 4096) ? Wdst : Wsrc;
    float* Osel = (o < 4096) ? Wda : Wsa;
    int oo = o & 4095;
    int r = oo >> 6, c = oo & 63;
    float acc = 0.f;
#pragma unroll
    for (int k = 0; k < 64; ++k) acc += Wsel[r * 64 + k] * A1[k * 64 + c];
    Osel[oo] = acc;
}

// ---- pack into MFMA A-fragment layout: fid 0=P2 1=A1 2=A2 3=Wout(hi) 4=Wout(lo)
__global__ void k_pack(const float* __restrict__ P2, const float* __restrict__ A1,
                       const float* __restrict__ A2, const float* __restrict__ Wout,
                       short* __restrict__ Apack) {
    int idx = blockIdx.x * 256 + threadIdx.x;   // fid*512 + (rb*2+s)*64 + l
    if (idx >= 2560) return;
    int l = idx & 63, s = (idx >> 6) & 1, rb = (idx >> 7) & 3, fid = idx >> 9;
    const float* W = (fid == 0) ? P2 : (fid == 1) ? A1 : (fid == 2) ? A2 : Wout;
    bool lo = (fid == 4);
#pragma unroll
    for (int b = 0; b < 8; ++b) {
        int in = 32 * s + 8 * (l >> 4) + b;
        int out = 16 * rb + (l & 15);
        float w = W[in * 64 + out];
        short hi = f2bf(w);
        Apack[idx * 8 + b] = lo ? f2bf(w - bf2f((unsigned short)hi)) : hi;
    }
}

// ---- merged node kernel: h=relu(x@Win+b) in reg; v=h@Wlin (fp32);
//      as1=h@Wsa (bf16); ad1=h@Wda+a1 (fp32); q=pos@P1 (bf16)
__global__ void __launch_bounds__(512) k_node(
    const float* __restrict__ x, const float* __restrict__ pos,
    const float* __restrict__ Win, const float* __restrict__ bin,
    const float* __restrict__ Wlin, const float* __restrict__ Wda,
    const float* __restrict__ Wsa, const float* __restrict__ P1,
    const float* __restrict__ a1,
    float* __restrict__ v, float* __restrict__ ad1,
    unsigned short* __restrict__ sb, unsigned short* __restrict__ qb) {
    __shared__ float Wi[4096], Wl[4096], Wd[4096], Ws[4096], Pb[320];
    for (int idx = threadIdx.x; idx < 4096; idx += 512) {
        Wi[idx] = Win[idx]; Wl[idx] = Wlin[idx]; Wd[idx] = Wda[idx]; Ws[idx] = Wsa[idx];
    }
    if (threadIdx.x < 192) Pb[threadIdx.x] = P1[threadIdx.x];
    if (threadIdx.x < 64) {
        Pb[192 + threadIdx.x] = bin[threadIdx.x];
        Pb[256 + threadIdx.x] = a1[threadIdx.x];
    }
    __syncthreads();
    int l = threadIdx.x & 63;
    int wid = blockIdx.x * 8 + (threadIdx.x >> 6);      // 0..4095
    for (int n = wid; n < NN; n += 4096) {
        float xv = x[(size_t)n * 64 + l];
        float p0 = pos[n * 3 + 0], p1v = pos[n * 3 + 1], p2v = pos[n * 3 + 2];
        float hv = Pb[192 + l];
#pragma unroll
        for (int k = 0; k < 64; ++k) hv += bcast(xv, k) * Wi[k * 64 + l];
        hv = frelu(hv);
        float av = 0.f, bv = Pb[256 + l], cv = 0.f;
#pragma unroll
        for (int k = 0; k < 64; ++k) {
            float s = bcast(hv, k);
            av += s * Wl[k * 64 + l];
            bv += s * Wd[k * 64 + l];
            cv += s * Ws[k * 64 + l];
        }
        v[(size_t)n * 64 + l] = av;
        ad1[(size_t)n * 64 + l] = bv;
        sb[(size_t)n * 64 + l] = (unsigned short)f2bf(cv);
        float qv = p0 * Pb[l] + p1v * Pb[64 + l] + p2v * Pb[128 + l];
        qb[(size_t)n * 64 + l] = (unsigned short)f2bf(qv);
    }
}

// ---- CSR build (padded to 16-edge tiles) ----
__global__ void k_hist(const int* __restrict__ ei, int* __restrict__ deg) {
    int e = blockIdx.x * 256 + threadIdx.x;
    atomicAdd(&deg[ei[NE + e]], 1);
}

__global__ void k_scan(const int* __restrict__ deg, int* __restrict__ poff,
                       int* __restrict__ cur) {
    __shared__ int part[256];
    int t = threadIdx.x;
    int sum = 0;
    for (int r = 0; r < 256; ++r) sum += ((deg[t * 256 + r] + 15) >> 4) << 4;
    part[t] = sum;
    __syncthreads();
    if (t == 0) {
        int run = 0;
        for (int b = 0; b < 256; ++b) { int tmp = part[b]; part[b] = run; run += tmp; }
    }
    __syncthreads();
    int run = part[t];
    for (int r = 0; r < 256; ++r) {
        int n = t * 256 + r;
        poff[n] = run; cur[n] = run;
        run += ((deg[n] + 15) >> 4) << 4;
    }
    if (t == 255) poff[NN] = run;
}

__global__ void k_scatter(const int* __restrict__ ei, int* __restrict__ cur,
                          int* __restrict__ srtj) {
    int e = blockIdx.x * 256 + threadIdx.x;
    int i = ei[NE + e];
    int slot = atomicAdd(&cur[i], 1);
    srtj[slot] = ei[e];
}

// D-layout -> next-layer B-frag transpose via shuffles.
__device__ __forceinline__ short8 transfrag(const f32x4* X, int s, int g, int e) {
    short8 r;
#pragma unroll
    for (int b = 0; b < 8; ++b) {
        float lo = X[2 * s][b & 3], hi = X[2 * s + 1][b & 3];
        float val = (g & 2) ? hi : lo;
        val = __shfl(val, 16 * (2 * (g & 1) + (b >> 2)) + e);
        r[b] = f2bf(val);
    }
    return r;
}

#define MFMA(a, b, c) __builtin_amdgcn_mfma_f32_16x16x32_bf16(a, b, c, 0, 0, 0)

// ---- persistent fused edge MLP (MFMA) + register softmax; q prefetched 1 tile ahead ----
__global__ void __launch_bounds__(256) k_edge(
    const unsigned short* __restrict__ qb, const float* __restrict__ ad1,
    const unsigned short* __restrict__ sb, const float* __restrict__ v,
    const int* __restrict__ poff, const int* __restrict__ deg,
    const int* __restrict__ srtj, const short* __restrict__ Apack,
    const float* __restrict__ p2b, const float* __restrict__ a2b,
    const float* __restrict__ p1b, float* __restrict__ o) {
    __shared__ short AwLds[12288];     // 3 layers x 4 rb x 2 s x 64 lanes x 8 bf16
    __shared__ float biasLds[192];     // [0]p2b [64]a2b [128]p1b
    {
        const int* gA = (const int*)Apack;
        int* sA = (int*)AwLds;
        for (int i = threadIdx.x; i < 6144; i += 256) sA[i] = gA[i];
        if (threadIdx.x < 64) {
            biasLds[threadIdx.x] = p2b[threadIdx.x];
            biasLds[64 + threadIdx.x] = a2b[threadIdx.x];
            biasLds[128 + threadIdx.x] = p1b[threadIdx.x];
        }
    }
    __syncthreads();

    int l = threadIdx.x & 63;
    int g = l >> 4, e = l & 15;
    int wid = blockIdx.x * 4 + (threadIdx.x >> 6);   // 0..EW-1

#define AW(L, rb, s) (*(const short8*)(AwLds + ((((L) * 4 + (rb)) * 2 + (s)) * 64 + l) * 8))

    // prologue: first node's CSR info + first tile's j and q data
    int t0 = poff[wid], t1 = poff[wid + 1], dn = deg[wid];
    int jcur = (t0 < t1) ? srtj[t0 + e] : 0;
    bf16x8 qA, qB;
    {
        const unsigned short* qr = qb + (size_t)jcur * 64;
        qA = *(const bf16x8*)(qr + 8 * g);
        qB = *(const bf16x8*)(qr + 32 + 8 * g);
    }

    for (int node = wid; node < NN; node += EW) {
        int nn = node + EW;
        int nt0 = 0, nt1 = 0, ndn = 0;
        if (nn < NN) { nt0 = poff[nn]; nt1 = poff[nn + 1]; ndn = deg[nn]; }
        int jf = (nn < NN && nt0 < nt1) ? srtj[nt0 + e] : 0;

        // per-node constants
        const unsigned short* qir = qb + (size_t)node * 64;
        bf16x8 qiA = *(const bf16x8*)(qir + 8 * g);
        bf16x8 qiB = *(const bf16x8*)(qir + 32 + 8 * g);
        f32x4 qpsA0, qpsA1, qpsB0, qpsB1;
#pragma unroll
        for (int b = 0; b < 4; ++b) {
            qpsA0[b] = bf2f(qiA[b])     + biasLds[128 + 8 * g + b];
            qpsA1[b] = bf2f(qiA[b + 4]) + biasLds[128 + 8 * g + 4 + b];
            qpsB0[b] = bf2f(qiB[b])     + biasLds[160 + 8 * g + b];
            qpsB1[b] = bf2f(qiB[b + 4]) + biasLds[160 + 8 * g + 4 + b];
        }
        f32x4 advv[4];
        const float* ai = ad1 + (size_t)node * 64;
#pragma unroll
        for (int rb = 0; rb < 4; ++rb) advv[rb] = *(const f32x4*)(ai + 16 * rb + 4 * g);

        f32x4 num[4], den[4];
#pragma unroll
        for (int rb = 0; rb < 4; ++rb) { num[rb] = (f32x4)0.f; den[rb] = (f32x4)0.f; }

        for (int tb = t0; tb < t1; tb += 16) {
            // ---- prefetch next tile's q (possibly next node's first tile) ----
            int jn = (tb + 16 < t1) ? srtj[tb + 16 + e] : jf;
            const unsigned short* qnr = qb + (size_t)jn * 64;
            bf16x8 nqA = *(const bf16x8*)(qnr + 8 * g);
            bf16x8 nqB = *(const bf16x8*)(qnr + 32 + 8 * g);
            // ---- issue current tile's as1/v early (consumed at layer 2 / epilogue) ----
            const unsigned short* srow = sb + (size_t)jcur * 64;
            bf16x4 sld[4];
#pragma unroll
            for (int rb = 0; rb < 4; ++rb)
                sld[rb] = *(const bf16x4*)(srow + 16 * rb + 4 * g);
            const float* vrow = v + (size_t)jcur * 64;
            f32x4 vld[4];
#pragma unroll
            for (int rb = 0; rb < 4; ++rb)
                vld[rb] = *(const f32x4*)(vrow + 16 * rb + 4 * g);

            // ---- u = lrelu(q_i + p1b - q_j) -> bf16 B-frags ----
            short8 bu0, bu1;
#pragma unroll
            for (int b = 0; b < 4; ++b) {
                bu0[b]     = f2bf(lrelu(qpsA0[b] - bf2f(qA[b])));
                bu0[b + 4] = f2bf(lrelu(qpsA1[b] - bf2f(qA[b + 4])));
                bu1[b]     = f2bf(lrelu(qpsB0[b] - bf2f(qB[b])));
                bu1[b + 4] = f2bf(lrelu(qpsB1[b] - bf2f(qB[b + 4])));
            }

            // layer 1: d^T = P2^T u^T + p2b
            f32x4 acc[4];
#pragma unroll
            for (int rb = 0; rb < 4; ++rb)
                acc[rb] = *(const f32x4*)(biasLds + 16 * rb + 4 * g);
#pragma unroll
            for (int rb = 0; rb < 4; ++rb) {
                acc[rb] = MFMA(AW(0, rb, 0), bu0, acc[rb]);
                acc[rb] = MFMA(AW(0, rb, 1), bu1, acc[rb]);
            }
            f32x4 d4[4];
#pragma unroll
            for (int rb = 0; rb < 4; ++rb)
#pragma unroll
                for (int c = 0; c < 4; ++c) { float xx = acc[rb][c]; d4[rb][c] = xx > 0.f ? xx : 0.01f * xx; }

            // layer 2: t^T = A1^T d^T + (adv_i - as1_j)
            short8 bd0 = transfrag(d4, 0, g, e);
            short8 bd1 = transfrag(d4, 1, g, e);
#pragma unroll
            for (int rb = 0; rb < 4; ++rb)
                acc[rb] = advv[rb] - b2f4(sld[rb]);
#pragma unroll
            for (int rb = 0; rb < 4; ++rb) {
                acc[rb] = MFMA(AW(1, rb, 0), bd0, acc[rb]);
                acc[rb] = MFMA(AW(1, rb, 1), bd1, acc[rb]);
            }
            f32x4 t4[4];
#pragma unroll
            for (int rb = 0; rb < 4; ++rb)
#pragma unroll
                for (int c = 0; c < 4; ++c) t4[rb][c] = frelu(acc[rb][c]);

            // layer 3: alpha^T = A2^T t^T + a2b
            short8 bt0 = transfrag(t4, 0, g, e);
            short8 bt1 = transfrag(t4, 1, g, e);
#pragma unroll
            for (int rb = 0; rb < 4; ++rb)
                acc[rb] = *(const f32x4*)(biasLds + 64 + 16 * rb + 4 * g);
#pragma unroll
            for (int rb = 0; rb < 4; ++rb) {
                acc[rb] = MFMA(AW(2, rb, 0), bt0, acc[rb]);
                acc[rb] = MFMA(AW(2, rb, 1), bt1, acc[rb]);
            }

            // softmax accumulate (alpha >= 0 -> exp safe, no max pass)
            bool ok = (tb - t0 + e) < dn;
#pragma unroll
            for (int rb = 0; rb < 4; ++rb) {
                f32x4 ew;
#pragma unroll
                for (int c = 0; c < 4; ++c) {
                    float a = frelu(acc[rb][c]);
                    ew[c] = ok ? __expf(a) : 0.f;
                }
                den[rb] += ew;
                num[rb] += ew * (vld[rb] + d4[rb]);
            }
            qA = nqA; qB = nqB; jcur = jn;
        }
        if (t0 == t1) {   // zero-degree node: keep the prefetch chain alive
            jcur = jf;
            const unsigned short* qr2 = qb + (size_t)jf * 64;
            qA = *(const bf16x8*)(qr2 + 8 * g);
            qB = *(const bf16x8*)(qr2 + 32 + 8 * g);
        }

        // reduce over the 16 edge-lanes
#pragma unroll
        for (int m = 1; m < 16; m <<= 1) {
#pragma unroll
            for (int rb = 0; rb < 4; ++rb)
#pragma unroll
                for (int c = 0; c < 4; ++c) {
                    num[rb][c] += __shfl_xor(num[rb][c], m);
                    den[rb][c] += __shfl_xor(den[rb][c], m);
                }
        }
        if (e == 0) {
            float* op = o + (size_t)node * 64;
#pragma unroll
            for (int rb = 0; rb < 4; ++rb) {
                f32x4 ov;
#pragma unroll
                for (int c = 0; c < 4; ++c) ov[c] = num[rb][c] / (den[rb][c] + 1e-16f);
                *(f32x4*)(op + 16 * rb + 4 * g) = ov;
            }
        }
        t0 = nt0; t1 = nt1; dn = ndn;
    }
#undef AW
}

// ---- out = relu(o @ Wout + bout), split-bf16 MFMA ----
__global__ void __launch_bounds__(512) k_out(const float* __restrict__ o,
                                             const short* __restrict__ Apack,
                                             const float* __restrict__ bout,
                                             float* __restrict__ out) {
    __shared__ short Ah[4096], Al[4096];
    __shared__ float bb[64];
    {
        const int* gh = (const int*)(Apack + 3 * 4096);
        const int* gl = (const int*)(Apack + 4 * 4096);
        int* sh = (int*)Ah; int* sl = (int*)Al;
        for (int i = threadIdx.x; i < 2048; i += 512) { sh[i] = gh[i]; sl[i] = gl[i]; }
        if (threadIdx.x < 64) bb[threadIdx.x] = bout[threadIdx.x];
    }
    __syncthreads();
    int l = threadIdx.x & 63, g = l >> 4;
    int tile = blockIdx.x * 8 + (threadIdx.x >> 6);   // 0..4095
    int nbase = tile * 16;
    const float* op = o + (size_t)(nbase + (l & 15)) * 64;
    f32x4 s0a = *(const f32x4*)(op + 8 * g);
    f32x4 s0b = *(const f32x4*)(op + 8 * g + 4);
    f32x4 s1a = *(const f32x4*)(op + 32 + 8 * g);
    f32x4 s1b = *(const f32x4*)(op + 36 + 8 * g);
    short8 bh0, bl0, bh1, bl1;
#pragma unroll
    for (int b = 0; b < 4; ++b) {
        short h;
        h = f2bf(s0a[b]); bh0[b] = h;     bl0[b] = f2bf(s0a[b] - bf2f((unsigned short)h));
        h = f2bf(s0b[b]); bh0[b + 4] = h; bl0[b + 4] = f2bf(s0b[b] - bf2f((unsigned short)h));
        h = f2bf(s1a[b]); bh1[b] = h;     bl1[b] = f2bf(s1a[b] - bf2f((unsigned short)h));
        h = f2bf(s1b[b]); bh1[b + 4] = h; bl1[b + 4] = f2bf(s1b[b] - bf2f((unsigned short)h));
    }
#define AF(arr, rb, s) (*(const short8*)(arr + (((rb) * 2 + (s)) * 64 + l) * 8))
    f32x4 acc[4];
#pragma unroll
    for (int rb = 0; rb < 4; ++rb) acc[rb] = *(const f32x4*)(bb + 16 * rb + 4 * g);
#pragma unroll
    for (int rb = 0; rb < 4; ++rb) {
        acc[rb] = MFMA(AF(Ah, rb, 0), bh0, acc[rb]);
        acc[rb] = MFMA(AF(Ah, rb, 1), bh1, acc[rb]);
        acc[rb] = MFMA(AF(Ah, rb, 0), bl0, acc[rb]);
        acc[rb] = MFMA(AF(Ah, rb, 1), bl1, acc[rb]);
        acc[rb] = MFMA(AF(Al, rb, 0), bh0, acc[rb]);
        acc[rb] = MFMA(AF(Al, rb, 1), bh1, acc[rb]);
    }
#undef AF
    float* outp = out + (size_t)(nbase + (l & 15)) * 64;
#pragma unroll
    for (int rb = 0; rb < 4; ++rb) {
        f32x4 r;
#pragma unroll
        for (int c = 0; c < 4; ++c) r[c] = frelu(acc[rb][c]);
        *(f32x4*)(outp + 16 * rb + 4 * g) = r;
    }
}

extern "C" void kernel_launch(void* const* d_in, const int* in_sizes, int n_in,
                              void* d_out, int out_size, void* d_ws, size_t ws_size,
                              hipStream_t stream) {
    const float* x    = (const float*)d_in[0];
    const float* pos  = (const float*)d_in[1];
    const int*   ei   = (const int*)d_in[2];
    const float* Win  = (const float*)d_in[3];
    const float* bin  = (const float*)d_in[4];
    const float* Wout = (const float*)d_in[5];
    const float* bout = (const float*)d_in[6];
    const float* Wlin = (const float*)d_in[7];
    const float* Wsrc = (const float*)d_in[8];
    const float* Wdst = (const float*)d_in[9];
    const float* P1   = (const float*)d_in[10];
    const float* p1   = (const float*)d_in[11];
    const float* P2   = (const float*)d_in[12];
    const float* p2   = (const float*)d_in[13];
    const float* A1   = (const float*)d_in[14];
    const float* a1   = (const float*)d_in[15];
    const float* A2   = (const float*)d_in[16];
    const float* a2   = (const float*)d_in[17];
    float* out = (float*)d_out;

    char* w = (char*)d_ws;
    float* Wda  = (float*)w; w += 4096 * 4;
    float* Wsa  = (float*)w; w += 4096 * 4;
    short* Apck = (short*)w; w += 5 * 4096 * 2;
    float* v    = (float*)w; w += (size_t)NN * 64 * 4;
    float* ad1  = (float*)w; w += (size_t)NN * 64 * 4;
    float* o    = (float*)w; w += (size_t)NN * 64 * 4;
    unsigned short* sbuf = (unsigned short*)w; w += (size_t)NN * 64 * 2;
    unsigned short* qbuf = (unsigned short*)w; w += (size_t)NN * 64 * 2;
    int* deg    = (int*)w; w += (size_t)NN * 4;
    int* poffp  = (int*)w; w += (size_t)(NN + 16) * 4;
    int* cur    = (int*)w; w += (size_t)NN * 4;
    int* srtj   = (int*)w; w += (size_t)2 * NE * 4;

    hipMemsetAsync(deg, 0, (size_t)NN * 4, stream);
    hipMemsetAsync(srtj, 0, (size_t)2 * NE * 4, stream);
    k_prep<<<32, 256, 0, stream>>>(Wdst, Wsrc, A1, Wda, Wsa);
    k_pack<<<10, 256, 0, stream>>>(P2, A1, A2, Wout, Apck);
    k_node<<<512, 512, 0, stream>>>(x, pos, Win, bin, Wlin, Wda, Wsa, P1, a1,
                                    v, ad1, sbuf, qbuf);
    k_hist<<<NE / 256, 256, 0, stream>>>(ei, deg);
    k_scan<<<1, 256, 0, stream>>>(deg, poffp, cur);
    k_scatter<<<NE / 256, 256, 0, stream>>>(ei, cur, srtj);
    k_edge<<<EW / 4, 256, 0, stream>>>(qbuf, ad1, sbuf, v, poffp, deg, srtj, Apck,
                                       p2, a2, p1, o);
    k_out<<<512, 512, 0, stream>>>(o, Apck, bout, out);
}